// Round 1
// baseline (15248.222 us; speedup 1.0000x reference)
//
#include <hip/hip_runtime.h>
#include <math.h>

// ---------------------------------------------------------------------------
// LapPyrNet forward — fp32 correctness-first implementation.
// ---------------------------------------------------------------------------

// Generic 3x3 SAME conv, NCHW. Supports concat of two input tensors along C
// (in1 first cin1 channels, in2 next cin2), optional residual add, activation
// (0=none, 1=relu, 2=lrelu 0.01). Each thread computes 4 output channels at
// one spatial position; blockIdx.y selects the group of 4 output channels.
__global__ __launch_bounds__(256) void conv3x3_k(
    const float* __restrict__ in1, long bs1, int cin1,
    const float* __restrict__ in2, long bs2, int cin2,
    const float* __restrict__ wgt, const float* __restrict__ bias,
    const float* __restrict__ res, long resbs,
    float* __restrict__ out, long outbs,
    int H, int W, int act)
{
    const int tid = threadIdx.x;
    const int pos = blockIdx.x * 256 + tid;
    const int HW = H * W;
    if (pos >= HW) return;
    const int h = pos / W, w = pos % W;
    const int b = blockIdx.z;
    const int co0 = blockIdx.y * 4;
    const int cin_tot = cin1 + cin2;
    const long wstride = (long)cin_tot * 9;
    float acc0 = bias[co0 + 0], acc1 = bias[co0 + 1];
    float acc2 = bias[co0 + 2], acc3 = bias[co0 + 3];
    for (int s = 0; s < 2; ++s) {
        const float* in = s ? in2 : in1;
        const int cin = s ? cin2 : cin1;
        if (cin == 0 || in == nullptr) continue;
        const long bs = s ? bs2 : bs1;
        const int coff = s ? cin1 : 0;
        const float* ib = in + (long)b * bs;
        for (int ci = 0; ci < cin; ++ci) {
            const float* ip = ib + (long)ci * HW;
            const float* wp = wgt + ((long)co0 * cin_tot + (coff + ci)) * 9;
            #pragma unroll
            for (int ky = 0; ky < 3; ++ky) {
                const int yy = h + ky - 1;
                const bool yv = (yy >= 0) && (yy < H);
                #pragma unroll
                for (int kx = 0; kx < 3; ++kx) {
                    const int xx = w + kx - 1;
                    const bool v = yv && (xx >= 0) && (xx < W);
                    const float xval = v ? ip[yy * W + xx] : 0.0f;
                    const int wi = ky * 3 + kx;
                    acc0 += xval * wp[wi];
                    acc1 += xval * wp[wstride + wi];
                    acc2 += xval * wp[2 * wstride + wi];
                    acc3 += xval * wp[3 * wstride + wi];
                }
            }
        }
    }
    float a[4] = {acc0, acc1, acc2, acc3};
    #pragma unroll
    for (int j = 0; j < 4; ++j) {
        float v = a[j];
        if (res) v += res[(long)b * resbs + (long)(co0 + j) * HW + pos];
        if (act == 1) v = fmaxf(v, 0.0f);
        else if (act == 2) v = (v >= 0.0f) ? v : 0.01f * v;
        out[(long)b * outbs + (long)(co0 + j) * HW + pos] = v;
    }
}

// MaxPool2d(3, stride 2, pad 1) followed by LeakyReLU(0.01). Planes merged
// over (B*C) in blockIdx.y.
__global__ __launch_bounds__(256) void pool_lrelu_k(
    const float* __restrict__ in, float* __restrict__ out, int H, int W)
{
    const int Ho = H / 2, Wo = W / 2;
    const int n = blockIdx.y;
    const int i = blockIdx.x * 256 + threadIdx.x;
    if (i >= Ho * Wo) return;
    const int ho = i / Wo, wo = i % Wo;
    const float* p = in + (long)n * H * W;
    float m = -1e30f;
    #pragma unroll
    for (int dy = 0; dy < 3; ++dy) {
        const int y = 2 * ho - 1 + dy;
        if (y < 0 || y >= H) continue;
        #pragma unroll
        for (int dx = 0; dx < 3; ++dx) {
            const int x = 2 * wo - 1 + dx;
            if (x < 0 || x >= W) continue;
            m = fmaxf(m, p[y * W + x]);
        }
    }
    out[(long)n * Ho * Wo + i] = (m >= 0.0f) ? m : 0.01f * m;
}

// Bilinear 2x upsample, half-pixel centers with edge clamp (== jax.image.resize
// 'bilinear' for 2x up), then multiply by 2.0 (po_up * 2 in reference).
__global__ __launch_bounds__(256) void resize2x_k(
    const float* __restrict__ in, float* __restrict__ out, int H, int W)
{
    const int Ho = 2 * H, Wo = 2 * W;
    const int n = blockIdx.y;
    const int i = blockIdx.x * 256 + threadIdx.x;
    if (i >= Ho * Wo) return;
    const int ho = i / Wo, wo = i % Wo;
    float cy = fminf(fmaxf(0.5f * (ho + 0.5f) - 0.5f, 0.0f), (float)(H - 1));
    float cx = fminf(fmaxf(0.5f * (wo + 0.5f) - 0.5f, 0.0f), (float)(W - 1));
    const int y0 = (int)cy, x0 = (int)cx;
    const int y1 = min(y0 + 1, H - 1), x1 = min(x0 + 1, W - 1);
    const float fy = cy - y0, fx = cx - x0;
    const float* p = in + (long)n * H * W;
    const float v = (1.0f - fy) * ((1.0f - fx) * p[y0 * W + x0] + fx * p[y0 * W + x1])
                  + fy * ((1.0f - fx) * p[y1 * W + x0] + fx * p[y1 * W + x1]);
    out[(long)n * Ho * Wo + i] = 2.0f * v;
}

// Copy a contiguous (B,64,H,W) tensor into the strided laps[:, view] slot.
__global__ __launch_bounds__(256) void copy_view_k(
    const float* __restrict__ src, float* __restrict__ dst, long dstbs, int n)
{
    const int i = blockIdx.x * 256 + threadIdx.x;
    const int b = blockIdx.y;
    if (i < n) dst[(long)b * dstbs + i] = src[(long)b * n + i];
}

// Modulated deformable conv v2 gather + 576-K reduction, fused.
// Block = 256 threads handles 32 spatial positions. Loops over the 8
// deformable groups; per group: sample 32x72 modulated bilinear values into
// LDS, stage the 64x72 weight slab into LDS, accumulate into registers.
// om layout: [B,216,H,W] = [dy(72) | dx(72) | mask(72)], channel g*9+k.
__global__ __launch_bounds__(256) void dcn_deform_k(
    const float* __restrict__ x, long xbs,
    const float* __restrict__ om,
    const float* __restrict__ wgt, const float* __restrict__ bias,
    float* __restrict__ out, int H, int W)
{
    __shared__ float val[32][73];
    __shared__ float wl[64][73];
    const int tid = threadIdx.x;
    const int b = blockIdx.y;
    const long HW = (long)H * W;
    const int pos0 = blockIdx.x * 32;
    const int o = tid & 63;       // output channel (compute phase)
    const int prow = tid >> 6;    // position block 0..3 (8 positions each)
    float acc[8];
    const float bv = bias[o];
    #pragma unroll
    for (int j = 0; j < 8; ++j) acc[j] = bv;
    const int sp = tid >> 3;      // sampling: position 0..31
    const int sc = tid & 7;       // sampling: channel within group 0..7
    const int pos_s = pos0 + sp;  // HW is a multiple of 32 for all levels
    const int hs = pos_s / W, ws_ = pos_s % W;
    const float* xb = x + (long)b * xbs;
    const float* omb = om + (long)b * 216 * HW;

    for (int g = 0; g < 8; ++g) {
        __syncthreads();  // previous iteration's compute must finish
        const float* xc = xb + (long)(g * 8 + sc) * HW;
        #pragma unroll
        for (int k = 0; k < 9; ++k) {
            const float dy = omb[(long)(g * 9 + k) * HW + pos_s];
            const float dx = omb[(long)(72 + g * 9 + k) * HW + pos_s];
            const float mv = omb[(long)(144 + g * 9 + k) * HW + pos_s];
            const float m = 1.0f / (1.0f + expf(-mv));
            float py = dy + (float)(hs + k / 3 - 1);
            float px = dx + (float)(ws_ + k % 3 - 1);
            py = fminf(fmaxf(py, -8.0f), (float)H + 8.0f);  // safe int cast
            px = fminf(fmaxf(px, -8.0f), (float)W + 8.0f);
            const float yf = floorf(py), xf = floorf(px);
            const float wy = py - yf, wx = px - xf;
            const int y0 = (int)yf, x0 = (int)xf;
            const int y1 = y0 + 1, x1 = x0 + 1;
            const bool yv0 = (y0 >= 0) && (y0 < H), yv1 = (y1 >= 0) && (y1 < H);
            const bool xv0 = (x0 >= 0) && (x0 < W), xv1 = (x1 >= 0) && (x1 < W);
            const int yc0 = min(max(y0, 0), H - 1), yc1 = min(max(y1, 0), H - 1);
            const int xc0 = min(max(x0, 0), W - 1), xc1 = min(max(x1, 0), W - 1);
            const float v00 = (yv0 && xv0) ? xc[(long)yc0 * W + xc0] : 0.0f;
            const float v01 = (yv0 && xv1) ? xc[(long)yc0 * W + xc1] : 0.0f;
            const float v10 = (yv1 && xv0) ? xc[(long)yc1 * W + xc0] : 0.0f;
            const float v11 = (yv1 && xv1) ? xc[(long)yc1 * W + xc1] : 0.0f;
            const float sv = (1.0f - wy) * ((1.0f - wx) * v00 + wx * v01)
                           + wy * ((1.0f - wx) * v10 + wx * v11);
            val[sp][sc * 9 + k] = sv * m;
        }
        for (int idx = tid; idx < 64 * 72; idx += 256) {
            const int oo = idx / 72, ii = idx % 72;
            wl[oo][ii] = wgt[(long)oo * 576 + g * 72 + ii];
        }
        __syncthreads();
        #pragma unroll 1
        for (int ii = 0; ii < 72; ++ii) {
            const float wv = wl[o][ii];
            #pragma unroll
            for (int p8 = 0; p8 < 8; ++p8)
                acc[p8] += val[prow * 8 + p8][ii] * wv;
        }
    }
    const long ob = (long)b * 64 * HW + (long)o * HW + pos0 + (long)prow * 8;
    #pragma unroll
    for (int p8 = 0; p8 < 8; ++p8) out[ob + p8] = acc[p8];
}

// ---------------------------------------------------------------------------
// Host-side orchestration
// ---------------------------------------------------------------------------

namespace {

struct OffParams {
    const float *c1w, *c1b, *rw1, *rb1, *rw2, *rb2, *c2w, *c2b;
};

inline void launch_conv(hipStream_t s,
                        const float* in1, long bs1, int c1,
                        const float* in2, long bs2, int c2,
                        const float* w, const float* b,
                        const float* res, long resbs,
                        float* out, long outbs,
                        int Cout, int H, int W, int B, int act)
{
    dim3 grid((H * W + 255) / 256, Cout / 4, B);
    conv3x3_k<<<grid, 256, 0, s>>>(in1, bs1, c1, in2, bs2, c2, w, b,
                                   res, resbs, out, outbs, H, W, act);
}

// offnet: lrelu(conv128->64) -> resblock x2 (shared params) -> lrelu(conv)
inline void run_offnet(hipStream_t s, const OffParams& p,
                       const float* cf, long cfbs, const float* lf, long lfbs,
                       float* t1, float* u, float* outp, int H, int W)
{
    const long hw = (long)H * W;
    launch_conv(s, cf, cfbs, 64, lf, lfbs, 64, p.c1w, p.c1b,
                nullptr, 0, t1, 64 * hw, 64, H, W, 2, 2);
    for (int r = 0; r < 2; ++r) {
        launch_conv(s, t1, 64 * hw, 64, nullptr, 0, 0, p.rw1, p.rb1,
                    nullptr, 0, u, 64 * hw, 64, H, W, 2, 1);
        launch_conv(s, u, 64 * hw, 64, nullptr, 0, 0, p.rw2, p.rb2,
                    t1, 64 * hw, t1, 64 * hw, 64, H, W, 2, 0);
    }
    launch_conv(s, t1, 64 * hw, 64, nullptr, 0, 0, p.c2w, p.c2b,
                nullptr, 0, outp, 64 * hw, 64, H, W, 2, 2);
}

// dcn: om conv (64->216) on feat, deformable gather+reduce, write back into
// the strided laps[:, view] slot through a temp (in-place hazard).
inline void run_dcn(hipStream_t s,
                    const float* xv, long xbs, const float* feat,
                    const float* omw, const float* ombias,
                    const float* w, const float* b,
                    float* om, float* tmp, float* dst, long dstbs,
                    int H, int W)
{
    const long hw = (long)H * W;
    launch_conv(s, feat, 64 * hw, 64, nullptr, 0, 0, omw, ombias,
                nullptr, 0, om, 216 * hw, 216, H, W, 2, 0);
    dim3 gd((H * W) / 32, 2);
    dcn_deform_k<<<gd, 256, 0, s>>>(xv, xbs, om, w, b, tmp, H, W);
    dim3 gc(((int)(64 * hw) + 255) / 256, 2);
    copy_view_k<<<gc, 256, 0, s>>>(tmp, dst, dstbs, (int)(64 * hw));
}

} // namespace

extern "C" void kernel_launch(void* const* d_in, const int* in_sizes, int n_in,
                              void* d_out, int out_size, void* d_ws, size_t ws_size,
                              hipStream_t stream)
{
    (void)in_sizes; (void)n_in; (void)out_size; (void)ws_size;
    const float* P[39];
    for (int k = 0; k < 39; ++k) P[k] = (const float*)d_in[k];
    const float* images  = P[0];
    const float* c0a_w = P[1];  const float* c0a_b = P[2];
    const float* c0r_w1 = P[3]; const float* c0r_b1 = P[4];
    const float* c0r_w2 = P[5]; const float* c0r_b2 = P[6];
    const float* c0b_w = P[7];  const float* c0b_b = P[8];
    const float* d_r1w1 = P[9];  const float* d_r1b1 = P[10];
    const float* d_r1w2 = P[11]; const float* d_r1b2 = P[12];
    const float* d_r2w1 = P[13]; const float* d_r2b1 = P[14];
    const float* d_r2w2 = P[15]; const float* d_r2b2 = P[16];
    const float* d_cw = P[17];   const float* d_cb = P[18];
    OffParams offp = {P[19], P[20], P[21], P[22], P[23], P[24], P[25], P[26]};
    OffParams mrgp = {P[27], P[28], P[29], P[30], P[31], P[32], P[33], P[34]};
    const float* dcn_om_w = P[35]; const float* dcn_om_b = P[36];
    const float* dcn_w = P[37];    const float* dcn_b = P[38];

    const int HW0 = 160 * 160, HW1 = 80 * 80, HW2 = 40 * 40;
    float* L0 = (float*)d_out;                 // (2,3,64,160,160)
    float* L1 = L0 + (long)6 * 64 * HW0;       // (2,3,64,80,80)
    float* L2 = L1 + (long)6 * 64 * HW1;       // (2,3,64,40,40)

    float* ws = (float*)d_ws;
    const long SZ6 = (long)6 * 64 * HW0;       // 9,830,400
    const long SZ2 = (long)2 * 64 * HW0;       // 3,276,800 (max view-loop buf)
    float* A  = ws;
    float* Bb = ws + SZ6;
    float* OM = ws + 2 * SZ6;                  // 2*216*HW0 = 11,059,200
    // view-loop overlays (feature extraction done by then):
    float* OFF1  = A;
    float* POUP  = A + SZ2;
    float* OFF   = A + 2 * SZ2;
    float* T1HID = Bb;
    float* U     = Bb + SZ2;
    float* TDCN  = Bb + 2 * SZ2;

    // ---------------- feature extraction (B = 6) ----------------
    launch_conv(stream, images, (long)3 * HW0, 3, nullptr, 0, 0, c0a_w, c0a_b,
                nullptr, 0, A, (long)64 * HW0, 64, 160, 160, 6, 0);
    launch_conv(stream, A, (long)64 * HW0, 64, nullptr, 0, 0, c0r_w1, c0r_b1,
                nullptr, 0, Bb, (long)64 * HW0, 64, 160, 160, 6, 1);
    launch_conv(stream, Bb, (long)64 * HW0, 64, nullptr, 0, 0, c0r_w2, c0r_b2,
                A, (long)64 * HW0, A, (long)64 * HW0, 64, 160, 160, 6, 0);
    launch_conv(stream, A, (long)64 * HW0, 64, nullptr, 0, 0, c0b_w, c0b_b,
                nullptr, 0, L0, (long)64 * HW0, 64, 160, 160, 6, 2);

    // down 160 -> 80 (input L0)
    launch_conv(stream, L0, (long)64 * HW0, 64, nullptr, 0, 0, d_r1w1, d_r1b1,
                nullptr, 0, Bb, (long)64 * HW0, 64, 160, 160, 6, 1);
    launch_conv(stream, Bb, (long)64 * HW0, 64, nullptr, 0, 0, d_r1w2, d_r1b2,
                L0, (long)64 * HW0, A, (long)64 * HW0, 64, 160, 160, 6, 0);
    launch_conv(stream, A, (long)64 * HW0, 64, nullptr, 0, 0, d_r2w1, d_r2b1,
                nullptr, 0, Bb, (long)64 * HW0, 64, 160, 160, 6, 1);
    launch_conv(stream, Bb, (long)64 * HW0, 64, nullptr, 0, 0, d_r2w2, d_r2b2,
                A, (long)64 * HW0, A, (long)64 * HW0, 64, 160, 160, 6, 0);
    launch_conv(stream, A, (long)64 * HW0, 64, nullptr, 0, 0, d_cw, d_cb,
                nullptr, 0, Bb, (long)64 * HW0, 64, 160, 160, 6, 0);
    {
        dim3 gp((HW1 + 255) / 256, 6 * 64);
        pool_lrelu_k<<<gp, 256, 0, stream>>>(Bb, L1, 160, 160);
    }
    // down 80 -> 40 (input L1)
    launch_conv(stream, L1, (long)64 * HW1, 64, nullptr, 0, 0, d_r1w1, d_r1b1,
                nullptr, 0, Bb, (long)64 * HW1, 64, 80, 80, 6, 1);
    launch_conv(stream, Bb, (long)64 * HW1, 64, nullptr, 0, 0, d_r1w2, d_r1b2,
                L1, (long)64 * HW1, A, (long)64 * HW1, 64, 80, 80, 6, 0);
    launch_conv(stream, A, (long)64 * HW1, 64, nullptr, 0, 0, d_r2w1, d_r2b1,
                nullptr, 0, Bb, (long)64 * HW1, 64, 80, 80, 6, 1);
    launch_conv(stream, Bb, (long)64 * HW1, 64, nullptr, 0, 0, d_r2w2, d_r2b2,
                A, (long)64 * HW1, A, (long)64 * HW1, 64, 80, 80, 6, 0);
    launch_conv(stream, A, (long)64 * HW1, 64, nullptr, 0, 0, d_cw, d_cb,
                nullptr, 0, Bb, (long)64 * HW1, 64, 80, 80, 6, 0);
    {
        dim3 gp((HW2 + 255) / 256, 6 * 64);
        pool_lrelu_k<<<gp, 256, 0, stream>>>(Bb, L2, 80, 80);
    }

    // ---------------- sequential view loop ----------------
    const int cv = 1;
    for (int view = 0; view < 3; ++view) {
        // level 2 (40x40): po = offnet(concat(center, view)); dcn update
        {
            const long lbs = (long)3 * 64 * HW2;
            const float* cf = L2 + (long)cv * 64 * HW2;
            const float* lf = L2 + (long)view * 64 * HW2;
            run_offnet(stream, offp, cf, lbs, lf, lbs, T1HID, U, OFF, 40, 40);
            run_dcn(stream, lf, lbs, OFF, dcn_om_w, dcn_om_b, dcn_w, dcn_b,
                    OM, TDCN, L2 + (long)view * 64 * HW2, lbs, 40, 40);
        }
        // level 1 (80x80)
        {
            const long lbs = (long)3 * 64 * HW1;
            const float* cf = L1 + (long)cv * 64 * HW1;
            const float* lf = L1 + (long)view * 64 * HW1;
            run_offnet(stream, offp, cf, lbs, lf, lbs, T1HID, U, OFF1, 80, 80);
            dim3 gr((HW1 + 255) / 256, 2 * 64);
            resize2x_k<<<gr, 256, 0, stream>>>(OFF, POUP, 40, 40); // po 40->80, *2
            run_offnet(stream, mrgp, OFF1, (long)64 * HW1, POUP, (long)64 * HW1,
                       T1HID, U, OFF, 80, 80);
            run_dcn(stream, lf, lbs, OFF, dcn_om_w, dcn_om_b, dcn_w, dcn_b,
                    OM, TDCN, L1 + (long)view * 64 * HW1, lbs, 80, 80);
        }
        // level 0 (160x160)
        {
            const long lbs = (long)3 * 64 * HW0;
            const float* cf = L0 + (long)cv * 64 * HW0;
            const float* lf = L0 + (long)view * 64 * HW0;
            run_offnet(stream, offp, cf, lbs, lf, lbs, T1HID, U, OFF1, 160, 160);
            dim3 gr((HW0 + 255) / 256, 2 * 64);
            resize2x_k<<<gr, 256, 0, stream>>>(OFF, POUP, 80, 80); // po 80->160, *2
            run_offnet(stream, mrgp, OFF1, (long)64 * HW0, POUP, (long)64 * HW0,
                       T1HID, U, OFF, 160, 160);
            run_dcn(stream, lf, lbs, OFF, dcn_om_w, dcn_om_b, dcn_w, dcn_b,
                    OM, TDCN, L0 + (long)view * 64 * HW0, lbs, 160, 160);
        }
    }
}

// Round 3
// 8565.853 us; speedup vs baseline: 1.7801x; 1.7801x over previous
//
#include <hip/hip_runtime.h>
#include <math.h>

using short8 = __attribute__((ext_vector_type(8))) short;
using f32x4  = __attribute__((ext_vector_type(4))) float;

__device__ __forceinline__ unsigned short f2bf(float f) {
    unsigned u = __builtin_bit_cast(unsigned, f);
    unsigned r = u + 0x7FFFu + ((u >> 16) & 1u);   // RNE
    return (unsigned short)(r >> 16);
}
__device__ __forceinline__ float bf2f(unsigned short h) {
    unsigned u = ((unsigned)h) << 16;
    return __builtin_bit_cast(float, u);
}

// ---------------------------------------------------------------------------
// Weight prep: fp32 OIHW(3x3) -> split-bf16 [cib16][Opad][tap*32 + q]
// q<16: hi(ci = cib*16+q), q>=16: lo(ci = cib*16+q-16). Zero-padded.
// ---------------------------------------------------------------------------
struct WDesc { const float* w; int Ci, O, Opad; long off; };
struct WDescs { WDesc d[18]; };

__global__ __launch_bounds__(256) void prep_w_k(WDescs ds, unsigned short* wp)
{
    const WDesc d = ds.d[blockIdx.y];
    const int ncib = (d.Ci + 15) >> 4;
    const int n = ncib * d.Opad * 288;
    const int idx = blockIdx.x * 256 + threadIdx.x;
    if (idx >= n) return;
    const int within = idx % 288;
    const int o = (idx / 288) % d.Opad;
    const int cib = idx / (288 * d.Opad);
    const int t = within >> 5, q = within & 31;
    const int ci = (cib << 4) + (q & 15);
    float v = 0.0f;
    if (o < d.O && ci < d.Ci) v = d.w[((long)o * d.Ci + ci) * 9 + t];
    const unsigned short hi = f2bf(v);
    const unsigned short lo = f2bf(v - bf2f(hi));
    wp[d.off + idx] = (q < 16) ? hi : lo;
}

// ---------------------------------------------------------------------------
// Split-bf16 MFMA conv3x3, SAME, NCHW. Exact fp32-equivalent products via the
// 2-MFMA half-swap trick. Concat of two inputs along C; optional residual;
// act: 0=none 1=relu 2=lrelu(0.01). Block: 4 waves, 64 out-ch x 16x16 pixels.
// ---------------------------------------------------------------------------
__global__ __launch_bounds__(256, 2) void conv_mfma_k(
    const float* __restrict__ in1, long bs1, int cin1,
    const float* __restrict__ in2, long bs2, int cin2,
    const unsigned short* __restrict__ wp,
    const float* __restrict__ bias,
    const float* __restrict__ res, long resbs,
    float* __restrict__ out, long outbs,
    int O, int H, int W, int act)
{
    __shared__ unsigned short in_t[12960];   // [18*18 px][40 stride, 32 used]
    __shared__ unsigned short w_t[18944];    // [64 co][296 stride, 288 used]
    const int tid = threadIdx.x;
    const int b = blockIdx.z;
    const int Opad = gridDim.y << 6;
    const int cobase = blockIdx.y << 6;
    const int tilesX = (W + 15) >> 4;
    const int tx = blockIdx.x % tilesX, ty = blockIdx.x / tilesX;
    const int x0 = tx << 4, y0 = ty << 4;
    const int HW = H * W;
    const int cin_tot = cin1 + cin2;
    const int ncib = (cin_tot + 15) >> 4;
    const int wv = tid >> 6, lane = tid & 63;
    const int lxx = lane & 15, kb = lane >> 4;

    f32x4 acc[4][4];
    #pragma unroll
    for (int i = 0; i < 4; ++i)
        #pragma unroll
        for (int j = 0; j < 4; ++j)
            acc[i][j] = (f32x4){0.f, 0.f, 0.f, 0.f};

    for (int cib = 0; cib < ncib; ++cib) {
        __syncthreads();
        // ---- stage weights: 64 x 288 packed slab -> LDS (stride 296) ----
        const unsigned short* slab = wp + ((long)cib * Opad + cobase) * 288;
        #pragma unroll
        for (int i = 0; i < 9; ++i) {
            const int c = tid + (i << 8);           // 2304 chunks of 8 bf16
            const int row = c / 36, col = c - row * 36;
            *(short8*)&w_t[row * 296 + (col << 3)] =
                *(const short8*)(slab + row * 288 + (col << 3));
        }
        // ---- stage input halo: 18x18 px, 16 real ch -> [hi(16)|lo(16)] ----
        if (tid < 144) {
            const int yy = tid >> 3, rp = tid & 7;  // row, real-ch pair
            const int g = (cib << 4) + (rp << 1);
            const float* s0 = nullptr;
            const float* s1 = nullptr;
            if (g < cin_tot)
                s0 = (g < cin1) ? in1 + (long)b * bs1 + (long)g * HW
                                : in2 + (long)b * bs2 + (long)(g - cin1) * HW;
            if (g + 1 < cin_tot)
                s1 = (g + 1 < cin1) ? in1 + (long)b * bs1 + (long)(g + 1) * HW
                                    : in2 + (long)b * bs2 + (long)(g + 1 - cin1) * HW;
            const int gy = y0 - 1 + yy;
            const bool yok = (gy >= 0) && (gy < H);
            #pragma unroll
            for (int xx = 0; xx < 18; ++xx) {
                const int gx = x0 - 1 + xx;
                const bool ok = yok && (gx >= 0) && (gx < W);
                const float v0 = (ok && s0) ? s0[gy * W + gx] : 0.0f;
                const float v1 = (ok && s1) ? s1[gy * W + gx] : 0.0f;
                const unsigned short h0 = f2bf(v0), h1 = f2bf(v1);
                const unsigned short l0 = f2bf(v0 - bf2f(h0));
                const unsigned short l1 = f2bf(v1 - bf2f(h1));
                unsigned short* base = &in_t[(yy * 18 + xx) * 40];
                *(unsigned*)(base + (rp << 1))      = (unsigned)h0 | ((unsigned)h1 << 16);
                *(unsigned*)(base + 16 + (rp << 1)) = (unsigned)l0 | ((unsigned)l1 << 16);
            }
        }
        __syncthreads();
        // ---- 9 taps x (4 Mtiles x 4 Ntiles x 2 terms) MFMA ----
        #pragma unroll
        for (int ky = 0; ky < 3; ++ky) {
            #pragma unroll
            for (int kx = 0; kx < 3; ++kx) {
                const int tap = ky * 3 + kx;
                short8 a[4], b1[4], b2[4];
                #pragma unroll
                for (int mt = 0; mt < 4; ++mt)
                    a[mt] = *(const short8*)&w_t[(mt * 16 + lxx) * 296 + tap * 32 + kb * 8];
                #pragma unroll
                for (int rr = 0; rr < 4; ++rr) {
                    const int pbase = ((wv * 4 + rr + ky) * 18 + lxx + kx) * 40;
                    b1[rr] = *(const short8*)&in_t[pbase + kb * 8];
                    b2[rr] = *(const short8*)&in_t[pbase + (kb ^ 2) * 8];
                }
                #pragma unroll
                for (int mt = 0; mt < 4; ++mt)
                    #pragma unroll
                    for (int rr = 0; rr < 4; ++rr) {
                        acc[mt][rr] = __builtin_amdgcn_mfma_f32_16x16x32_bf16(
                            a[mt], b1[rr], acc[mt][rr], 0, 0, 0);
                        acc[mt][rr] = __builtin_amdgcn_mfma_f32_16x16x32_bf16(
                            a[mt], b2[rr], acc[mt][rr], 0, 0, 0);
                    }
            }
        }
    }

    // ---- epilogue (C/D: col=lane&15 -> pixel x, row=kb*4+j -> out-ch) ----
    const int x = x0 + lxx;
    const bool xok = (x < W);
    #pragma unroll
    for (int mt = 0; mt < 4; ++mt) {
        const int col0 = cobase + mt * 16 + kb * 4;
        float bvv[4];
        #pragma unroll
        for (int j = 0; j < 4; ++j)
            bvv[j] = (col0 + j < O) ? bias[col0 + j] : 0.0f;
        #pragma unroll
        for (int rr = 0; rr < 4; ++rr) {
            const int y = y0 + wv * 4 + rr;
            if (y >= H) continue;
            #pragma unroll
            for (int j = 0; j < 4; ++j) {
                const int coj = col0 + j;
                if (coj >= O || !xok) continue;
                float v = acc[mt][rr][j] + bvv[j];
                const long oidx = (long)b * outbs + (long)coj * HW + (long)y * W + x;
                if (res) v += res[(long)b * resbs + (long)coj * HW + (long)y * W + x];
                if (act == 1) v = fmaxf(v, 0.0f);
                else if (act == 2) v = (v >= 0.0f) ? v : 0.01f * v;
                out[oidx] = v;
            }
        }
    }
}

// ---------------------------------------------------------------------------
// MaxPool2d(3,2,1) + LeakyReLU
// ---------------------------------------------------------------------------
__global__ __launch_bounds__(256) void pool_lrelu_k(
    const float* __restrict__ in, float* __restrict__ out, int H, int W)
{
    const int Ho = H / 2, Wo = W / 2;
    const int n = blockIdx.y;
    const int i = blockIdx.x * 256 + threadIdx.x;
    if (i >= Ho * Wo) return;
    const int ho = i / Wo, wo = i % Wo;
    const float* p = in + (long)n * H * W;
    float m = -1e30f;
    #pragma unroll
    for (int dy = 0; dy < 3; ++dy) {
        const int y = 2 * ho - 1 + dy;
        if (y < 0 || y >= H) continue;
        #pragma unroll
        for (int dx = 0; dx < 3; ++dx) {
            const int x = 2 * wo - 1 + dx;
            if (x < 0 || x >= W) continue;
            m = fmaxf(m, p[y * W + x]);
        }
    }
    out[(long)n * Ho * Wo + i] = (m >= 0.0f) ? m : 0.01f * m;
}

// Bilinear 2x upsample (half-pixel, edge clamp) then *2.0
__global__ __launch_bounds__(256) void resize2x_k(
    const float* __restrict__ in, float* __restrict__ out, int H, int W)
{
    const int Ho = 2 * H, Wo = 2 * W;
    const int n = blockIdx.y;
    const int i = blockIdx.x * 256 + threadIdx.x;
    if (i >= Ho * Wo) return;
    const int ho = i / Wo, wo = i % Wo;
    float cy = fminf(fmaxf(0.5f * (ho + 0.5f) - 0.5f, 0.0f), (float)(H - 1));
    float cx = fminf(fmaxf(0.5f * (wo + 0.5f) - 0.5f, 0.0f), (float)(W - 1));
    const int y0 = (int)cy, x0 = (int)cx;
    const int y1 = min(y0 + 1, H - 1), x1 = min(x0 + 1, W - 1);
    const float fy = cy - y0, fx = cx - x0;
    const float* p = in + (long)n * H * W;
    const float v = (1.0f - fy) * ((1.0f - fx) * p[y0 * W + x0] + fx * p[y0 * W + x1])
                  + fy * ((1.0f - fx) * p[y1 * W + x0] + fx * p[y1 * W + x1]);
    out[(long)n * Ho * Wo + i] = 2.0f * v;
}

__global__ __launch_bounds__(256) void copy_view_k(
    const float* __restrict__ src, float* __restrict__ dst, long dstbs, int n)
{
    const int i = blockIdx.x * 256 + threadIdx.x;
    const int b = blockIdx.y;
    if (i < n) dst[(long)b * dstbs + i] = src[(long)b * n + i];
}

// ---------------------------------------------------------------------------
// Modulated deformable conv v2 (fp32), fused gather + 576-K reduction.
// ---------------------------------------------------------------------------
__global__ __launch_bounds__(256) void dcn_deform_k(
    const float* __restrict__ x, long xbs,
    const float* __restrict__ om,
    const float* __restrict__ wgt, const float* __restrict__ bias,
    float* __restrict__ out, int H, int W)
{
    __shared__ float val[32][73];
    __shared__ float wl[64][73];
    const int tid = threadIdx.x;
    const int b = blockIdx.y;
    const long HW = (long)H * W;
    const int pos0 = blockIdx.x * 32;
    const int o = tid & 63;
    const int prow = tid >> 6;
    float acc[8];
    const float bv = bias[o];
    #pragma unroll
    for (int j = 0; j < 8; ++j) acc[j] = bv;
    const int sp = tid >> 3;
    const int sc = tid & 7;
    const int pos_s = pos0 + sp;
    const int hs = pos_s / W, ws_ = pos_s % W;
    const float* xb = x + (long)b * xbs;
    const float* omb = om + (long)b * 216 * HW;

    for (int g = 0; g < 8; ++g) {
        __syncthreads();
        const float* xc = xb + (long)(g * 8 + sc) * HW;
        #pragma unroll
        for (int k = 0; k < 9; ++k) {
            const float dy = omb[(long)(g * 9 + k) * HW + pos_s];
            const float dx = omb[(long)(72 + g * 9 + k) * HW + pos_s];
            const float mv = omb[(long)(144 + g * 9 + k) * HW + pos_s];
            const float m = 1.0f / (1.0f + expf(-mv));
            float py = dy + (float)(hs + k / 3 - 1);
            float px = dx + (float)(ws_ + k % 3 - 1);
            py = fminf(fmaxf(py, -8.0f), (float)H + 8.0f);
            px = fminf(fmaxf(px, -8.0f), (float)W + 8.0f);
            const float yf = floorf(py), xf = floorf(px);
            const float wy = py - yf, wx = px - xf;
            const int y0 = (int)yf, x0 = (int)xf;
            const int y1 = y0 + 1, x1 = x0 + 1;
            const bool yv0 = (y0 >= 0) && (y0 < H), yv1 = (y1 >= 0) && (y1 < H);
            const bool xv0 = (x0 >= 0) && (x0 < W), xv1 = (x1 >= 0) && (x1 < W);
            const int yc0 = min(max(y0, 0), H - 1), yc1 = min(max(y1, 0), H - 1);
            const int xc0 = min(max(x0, 0), W - 1), xc1 = min(max(x1, 0), W - 1);
            const float v00 = (yv0 && xv0) ? xc[(long)yc0 * W + xc0] : 0.0f;
            const float v01 = (yv0 && xv1) ? xc[(long)yc0 * W + xc1] : 0.0f;
            const float v10 = (yv1 && xv0) ? xc[(long)yc1 * W + xc0] : 0.0f;
            const float v11 = (yv1 && xv1) ? xc[(long)yc1 * W + xc1] : 0.0f;
            const float sv = (1.0f - wy) * ((1.0f - wx) * v00 + wx * v01)
                           + wy * ((1.0f - wx) * v10 + wx * v11);
            val[sp][sc * 9 + k] = sv * m;
        }
        for (int idx = tid; idx < 64 * 72; idx += 256) {
            const int oo = idx / 72, ii = idx % 72;
            wl[oo][ii] = wgt[(long)oo * 576 + g * 72 + ii];
        }
        __syncthreads();
        #pragma unroll 1
        for (int ii = 0; ii < 72; ++ii) {
            const float wv = wl[o][ii];
            #pragma unroll
            for (int p8 = 0; p8 < 8; ++p8)
                acc[p8] += val[prow * 8 + p8][ii] * wv;
        }
    }
    const long ob = (long)b * 64 * HW + (long)o * HW + pos0 + (long)prow * 8;
    #pragma unroll
    for (int p8 = 0; p8 < 8; ++p8) out[ob + p8] = acc[p8];
}

// ---------------------------------------------------------------------------
// Host orchestration
// ---------------------------------------------------------------------------
namespace {

struct MOff {
    const unsigned short *c1w; const float* c1b;
    const unsigned short *rw1; const float* rb1;
    const unsigned short *rw2; const float* rb2;
    const unsigned short *c2w; const float* c2b;
};

inline void launch_mconv(hipStream_t s,
                         const float* in1, long bs1, int c1,
                         const float* in2, long bs2, int c2,
                         const unsigned short* wpp, const float* bias,
                         const float* res, long resbs,
                         float* out, long outbs,
                         int O, int Opad, int H, int W, int B, int act)
{
    dim3 grid(((H + 15) / 16) * ((W + 15) / 16), Opad / 64, B);
    conv_mfma_k<<<grid, 256, 0, s>>>(in1, bs1, c1, in2, bs2, c2, wpp, bias,
                                     res, resbs, out, outbs, O, H, W, act);
}

inline void run_offnet(hipStream_t s, const MOff& p,
                       const float* cf, long cfbs, const float* lf, long lfbs,
                       float* t1, float* u, float* outp, int H, int W)
{
    const long hw = (long)H * W;
    launch_mconv(s, cf, cfbs, 64, lf, lfbs, 64, p.c1w, p.c1b,
                 nullptr, 0, t1, 64 * hw, 64, 64, H, W, 2, 2);
    for (int r = 0; r < 2; ++r) {
        launch_mconv(s, t1, 64 * hw, 64, nullptr, 0, 0, p.rw1, p.rb1,
                     nullptr, 0, u, 64 * hw, 64, 64, H, W, 2, 1);
        launch_mconv(s, u, 64 * hw, 64, nullptr, 0, 0, p.rw2, p.rb2,
                     t1, 64 * hw, t1, 64 * hw, 64, 64, H, W, 2, 0);
    }
    launch_mconv(s, t1, 64 * hw, 64, nullptr, 0, 0, p.c2w, p.c2b,
                 nullptr, 0, outp, 64 * hw, 64, 64, H, W, 2, 2);
}

inline void run_dcn(hipStream_t s,
                    const float* xv, long xbs, const float* feat,
                    const unsigned short* omw, const float* ombias,
                    const float* w, const float* b,
                    float* om, float* tmp, float* dst, long dstbs,
                    int H, int W)
{
    const long hw = (long)H * W;
    launch_mconv(s, feat, 64 * hw, 64, nullptr, 0, 0, omw, ombias,
                 nullptr, 0, om, 216 * hw, 216, 256, H, W, 2, 0);
    dim3 gd((H * W) / 32, 2);
    dcn_deform_k<<<gd, 256, 0, s>>>(xv, xbs, om, w, b, tmp, H, W);
    dim3 gc(((int)(64 * hw) + 255) / 256, 2);
    copy_view_k<<<gc, 256, 0, s>>>(tmp, dst, dstbs, (int)(64 * hw));
}

} // namespace

extern "C" void kernel_launch(void* const* d_in, const int* in_sizes, int n_in,
                              void* d_out, int out_size, void* d_ws, size_t ws_size,
                              hipStream_t stream)
{
    (void)in_sizes; (void)n_in; (void)out_size; (void)ws_size;
    const float* P[39];
    for (int k = 0; k < 39; ++k) P[k] = (const float*)d_in[k];
    const float* images = P[0];

    const int HW0 = 160 * 160, HW1 = 80 * 80, HW2 = 40 * 40;
    float* L0 = (float*)d_out;
    float* L1 = L0 + (long)6 * 64 * HW0;
    float* L2 = L1 + (long)6 * 64 * HW1;

    float* ws = (float*)d_ws;
    const long SZ6 = (long)6 * 64 * HW0;
    const long SZ2 = (long)2 * 64 * HW0;
    const long OMsz = (long)2 * 216 * HW0;
    float* A  = ws;
    float* Bb = ws + SZ6;
    float* OM = ws + 2 * SZ6;
    unsigned short* WP = (unsigned short*)(ws + 2 * SZ6 + OMsz);
    // view-loop overlays
    float* OFF1  = A;
    float* POUP  = A + SZ2;
    float* OFF   = A + 2 * SZ2;
    float* T1HID = Bb;
    float* U     = Bb + SZ2;
    float* TDCN  = Bb + 2 * SZ2;

    // ---- weight prep descriptors ----
    const int widx[18] = {1,3,5,7,9,11,13,15,17,19,21,23,25,27,29,31,33,35};
    const int wci[18]  = {3,64,64,64,64,64,64,64,64,128,64,64,64,128,64,64,64,64};
    const int wo_[18]  = {64,64,64,64,64,64,64,64,64,64,64,64,64,64,64,64,64,216};
    WDescs ds;
    long off = 0;
    long woff[18];
    for (int i = 0; i < 18; ++i) {
        const int opad = (wo_[i] + 63) / 64 * 64;
        const int ncib = (wci[i] + 15) / 16;
        ds.d[i].w = P[widx[i]]; ds.d[i].Ci = wci[i]; ds.d[i].O = wo_[i];
        ds.d[i].Opad = opad; ds.d[i].off = off;
        woff[i] = off;
        off += (long)ncib * opad * 288;
    }
    prep_w_k<<<dim3(1152, 18), 256, 0, stream>>>(ds, WP);

    const unsigned short* Wc0a  = WP + woff[0];
    const unsigned short* Wc0r1 = WP + woff[1];
    const unsigned short* Wc0r2 = WP + woff[2];
    const unsigned short* Wc0b  = WP + woff[3];
    const unsigned short* Wd11  = WP + woff[4];
    const unsigned short* Wd12  = WP + woff[5];
    const unsigned short* Wd21  = WP + woff[6];
    const unsigned short* Wd22  = WP + woff[7];
    const unsigned short* Wdc   = WP + woff[8];
    MOff offp = {WP + woff[9],  P[20], WP + woff[10], P[22],
                 WP + woff[11], P[24], WP + woff[12], P[26]};
    MOff mrgp = {WP + woff[13], P[28], WP + woff[14], P[30],
                 WP + woff[15], P[32], WP + woff[16], P[34]};
    const unsigned short* Wom = WP + woff[17];
    const float* dcn_om_b = P[36];
    const float* dcn_w = P[37];
    const float* dcn_b = P[38];

    // ---------------- feature extraction (B = 6) ----------------
    launch_mconv(stream, images, (long)3 * HW0, 3, nullptr, 0, 0, Wc0a, P[2],
                 nullptr, 0, A, (long)64 * HW0, 64, 64, 160, 160, 6, 0);
    launch_mconv(stream, A, (long)64 * HW0, 64, nullptr, 0, 0, Wc0r1, P[4],
                 nullptr, 0, Bb, (long)64 * HW0, 64, 64, 160, 160, 6, 1);
    launch_mconv(stream, Bb, (long)64 * HW0, 64, nullptr, 0, 0, Wc0r2, P[6],
                 A, (long)64 * HW0, A, (long)64 * HW0, 64, 64, 160, 160, 6, 0);
    launch_mconv(stream, A, (long)64 * HW0, 64, nullptr, 0, 0, Wc0b, P[8],
                 nullptr, 0, L0, (long)64 * HW0, 64, 64, 160, 160, 6, 2);

    launch_mconv(stream, L0, (long)64 * HW0, 64, nullptr, 0, 0, Wd11, P[10],
                 nullptr, 0, Bb, (long)64 * HW0, 64, 64, 160, 160, 6, 1);
    launch_mconv(stream, Bb, (long)64 * HW0, 64, nullptr, 0, 0, Wd12, P[12],
                 L0, (long)64 * HW0, A, (long)64 * HW0, 64, 64, 160, 160, 6, 0);
    launch_mconv(stream, A, (long)64 * HW0, 64, nullptr, 0, 0, Wd21, P[14],
                 nullptr, 0, Bb, (long)64 * HW0, 64, 64, 160, 160, 6, 1);
    launch_mconv(stream, Bb, (long)64 * HW0, 64, nullptr, 0, 0, Wd22, P[16],
                 A, (long)64 * HW0, A, (long)64 * HW0, 64, 64, 160, 160, 6, 0);
    launch_mconv(stream, A, (long)64 * HW0, 64, nullptr, 0, 0, Wdc, P[18],
                 nullptr, 0, Bb, (long)64 * HW0, 64, 64, 160, 160, 6, 0);
    {
        dim3 gp((HW1 + 255) / 256, 6 * 64);
        pool_lrelu_k<<<gp, 256, 0, stream>>>(Bb, L1, 160, 160);
    }
    launch_mconv(stream, L1, (long)64 * HW1, 64, nullptr, 0, 0, Wd11, P[10],
                 nullptr, 0, Bb, (long)64 * HW1, 64, 64, 80, 80, 6, 1);
    launch_mconv(stream, Bb, (long)64 * HW1, 64, nullptr, 0, 0, Wd12, P[12],
                 L1, (long)64 * HW1, A, (long)64 * HW1, 64, 64, 80, 80, 6, 0);
    launch_mconv(stream, A, (long)64 * HW1, 64, nullptr, 0, 0, Wd21, P[14],
                 nullptr, 0, Bb, (long)64 * HW1, 64, 64, 80, 80, 6, 1);
    launch_mconv(stream, Bb, (long)64 * HW1, 64, nullptr, 0, 0, Wd22, P[16],
                 A, (long)64 * HW1, A, (long)64 * HW1, 64, 64, 80, 80, 6, 0);
    launch_mconv(stream, A, (long)64 * HW1, 64, nullptr, 0, 0, Wdc, P[18],
                 nullptr, 0, Bb, (long)64 * HW1, 64, 64, 80, 80, 6, 0);
    {
        dim3 gp((HW2 + 255) / 256, 6 * 64);
        pool_lrelu_k<<<gp, 256, 0, stream>>>(Bb, L2, 80, 80);
    }

    // ---------------- sequential view loop ----------------
    const int cv = 1;
    for (int view = 0; view < 3; ++view) {
        {
            const long lbs = (long)3 * 64 * HW2;
            const float* cf = L2 + (long)cv * 64 * HW2;
            const float* lf = L2 + (long)view * 64 * HW2;
            run_offnet(stream, offp, cf, lbs, lf, lbs, T1HID, U, OFF, 40, 40);
            run_dcn(stream, lf, lbs, OFF, Wom, dcn_om_b, dcn_w, dcn_b,
                    OM, TDCN, L2 + (long)view * 64 * HW2, lbs, 40, 40);
        }
        {
            const long lbs = (long)3 * 64 * HW1;
            const float* cf = L1 + (long)cv * 64 * HW1;
            const float* lf = L1 + (long)view * 64 * HW1;
            run_offnet(stream, offp, cf, lbs, lf, lbs, T1HID, U, OFF1, 80, 80);
            dim3 gr((HW1 + 255) / 256, 2 * 64);
            resize2x_k<<<gr, 256, 0, stream>>>(OFF, POUP, 40, 40);
            run_offnet(stream, mrgp, OFF1, (long)64 * HW1, POUP, (long)64 * HW1,
                       T1HID, U, OFF, 80, 80);
            run_dcn(stream, lf, lbs, OFF, Wom, dcn_om_b, dcn_w, dcn_b,
                    OM, TDCN, L1 + (long)view * 64 * HW1, lbs, 80, 80);
        }
        {
            const long lbs = (long)3 * 64 * HW0;
            const float* cf = L0 + (long)cv * 64 * HW0;
            const float* lf = L0 + (long)view * 64 * HW0;
            run_offnet(stream, offp, cf, lbs, lf, lbs, T1HID, U, OFF1, 160, 160);
            dim3 gr((HW0 + 255) / 256, 2 * 64);
            resize2x_k<<<gr, 256, 0, stream>>>(OFF, POUP, 80, 80);
            run_offnet(stream, mrgp, OFF1, (long)64 * HW0, POUP, (long)64 * HW0,
                       T1HID, U, OFF, 160, 160);
            run_dcn(stream, lf, lbs, OFF, Wom, dcn_om_b, dcn_w, dcn_b,
                    OM, TDCN, L0 + (long)view * 64 * HW0, lbs, 160, 160);
        }
    }
}

// Round 5
// 6754.907 us; speedup vs baseline: 2.2574x; 1.2681x over previous
//
#include <hip/hip_runtime.h>
#include <math.h>

using short8 = __attribute__((ext_vector_type(8))) short;
using f32x4  = __attribute__((ext_vector_type(4))) float;

struct Tab8 { long o[8]; };

__device__ __forceinline__ unsigned short f2bf(float f) {
    unsigned u = __builtin_bit_cast(unsigned, f);
    unsigned r = u + 0x7FFFu + ((u >> 16) & 1u);   // RNE
    return (unsigned short)(r >> 16);
}
__device__ __forceinline__ float bf2f(unsigned short h) {
    unsigned u = ((unsigned)h) << 16;
    return __builtin_bit_cast(float, u);
}

// ---------------------------------------------------------------------------
// Conv weight prep: fp32 OIHW(3x3) -> split-bf16 [cib16][Opad][tap*32 + q]
// q<16: hi(ci=cib*16+q), q>=16: lo. Zero padded.
// ---------------------------------------------------------------------------
struct WDesc { const float* w; int Ci, O, Opad; long off; };
struct WDescs { WDesc d[18]; };

__global__ __launch_bounds__(256) void prep_w_k(WDescs ds, unsigned short* wp)
{
    const WDesc d = ds.d[blockIdx.y];
    const int ncib = (d.Ci + 15) >> 4;
    const int n = ncib * d.Opad * 288;
    const int idx = blockIdx.x * 256 + threadIdx.x;
    if (idx >= n) return;
    const int within = idx % 288;
    const int o = (idx / 288) % d.Opad;
    const int cib = idx / (288 * d.Opad);
    const int t = within >> 5, q = within & 31;
    const int ci = (cib << 4) + (q & 15);
    float v = 0.0f;
    if (o < d.O && ci < d.Ci) v = d.w[((long)o * d.Ci + ci) * 9 + t];
    const unsigned short hi = f2bf(v);
    const unsigned short lo = f2bf(v - bf2f(hi));
    wp[d.off + idx] = (q < 16) ? hi : lo;
}

// DCN weight prep: fp32 [64][576] -> split-bf16 [kb=36][o=64][q=32]
__global__ __launch_bounds__(256) void prep_dcnw_k(const float* __restrict__ w,
                                                   unsigned short* __restrict__ out)
{
    const int idx = blockIdx.x * 256 + threadIdx.x;
    if (idx >= 36 * 64 * 32) return;
    const int q = idx & 31, o = (idx >> 5) & 63, kb = idx >> 11;
    const float v = w[o * 576 + kb * 16 + (q & 15)];
    const unsigned short hi = f2bf(v);
    out[idx] = (q < 16) ? hi : f2bf(v - bf2f(hi));
}

// ---------------------------------------------------------------------------
// Split-bf16 MFMA conv3x3, SAME, NCHW, per-batch offset tables.
// act: 0=none 1=relu 2=lrelu(0.01). Block: 4 waves, 64 out-ch x 16x16 px.
// ---------------------------------------------------------------------------
__global__ __launch_bounds__(256, 2) void conv_mfma_k(
    const float* __restrict__ in1, Tab8 t1, int cin1,
    const float* __restrict__ in2, Tab8 t2, int cin2,
    const unsigned short* __restrict__ wp,
    const float* __restrict__ bias,
    const float* __restrict__ res, Tab8 trr, int hasres,
    float* __restrict__ out, Tab8 to,
    int O, int H, int W, int act)
{
    __shared__ unsigned short in_t[12960];   // [18*18 px][40 stride, 32 used]
    __shared__ unsigned short w_t[18944];    // [64 co][296 stride, 288 used]
    const int tid = threadIdx.x;
    const int b = blockIdx.z;
    const int Opad = gridDim.y << 6;
    const int cobase = blockIdx.y << 6;
    const int tilesX = (W + 15) >> 4;
    const int tx = blockIdx.x % tilesX, ty = blockIdx.x / tilesX;
    const int x0 = tx << 4, y0 = ty << 4;
    const int HW = H * W;
    const int cin_tot = cin1 + cin2;
    const int ncib = (cin_tot + 15) >> 4;
    const int wv = tid >> 6, lane = tid & 63;
    const int lxx = lane & 15, kb = lane >> 4;
    const long o1 = t1.o[b], o2 = t2.o[b];

    f32x4 acc[4][4];
    #pragma unroll
    for (int i = 0; i < 4; ++i)
        #pragma unroll
        for (int j = 0; j < 4; ++j)
            acc[i][j] = (f32x4){0.f, 0.f, 0.f, 0.f};

    for (int cib = 0; cib < ncib; ++cib) {
        __syncthreads();
        const unsigned short* slab = wp + ((long)cib * Opad + cobase) * 288;
        #pragma unroll
        for (int i = 0; i < 9; ++i) {
            const int c = tid + (i << 8);
            const int row = c / 36, col = c - row * 36;
            *(short8*)&w_t[row * 296 + (col << 3)] =
                *(const short8*)(slab + row * 288 + (col << 3));
        }
        if (tid < 144) {
            const int yy = tid >> 3, rp = tid & 7;
            const int g = (cib << 4) + (rp << 1);
            const float* s0 = nullptr;
            const float* s1 = nullptr;
            if (g < cin_tot)
                s0 = (g < cin1) ? in1 + o1 + (long)g * HW
                                : in2 + o2 + (long)(g - cin1) * HW;
            if (g + 1 < cin_tot)
                s1 = (g + 1 < cin1) ? in1 + o1 + (long)(g + 1) * HW
                                    : in2 + o2 + (long)(g + 1 - cin1) * HW;
            const int gy = y0 - 1 + yy;
            const bool yok = (gy >= 0) && (gy < H);
            #pragma unroll
            for (int xx = 0; xx < 18; ++xx) {
                const int gx = x0 - 1 + xx;
                const bool ok = yok && (gx >= 0) && (gx < W);
                const float v0 = (ok && s0) ? s0[gy * W + gx] : 0.0f;
                const float v1 = (ok && s1) ? s1[gy * W + gx] : 0.0f;
                const unsigned short h0 = f2bf(v0), h1 = f2bf(v1);
                const unsigned short l0 = f2bf(v0 - bf2f(h0));
                const unsigned short l1 = f2bf(v1 - bf2f(h1));
                unsigned short* base = &in_t[(yy * 18 + xx) * 40];
                *(unsigned*)(base + (rp << 1))      = (unsigned)h0 | ((unsigned)h1 << 16);
                *(unsigned*)(base + 16 + (rp << 1)) = (unsigned)l0 | ((unsigned)l1 << 16);
            }
        }
        __syncthreads();
        #pragma unroll
        for (int ky = 0; ky < 3; ++ky) {
            #pragma unroll
            for (int kx = 0; kx < 3; ++kx) {
                const int tap = ky * 3 + kx;
                short8 a[4], b1[4], b2[4];
                #pragma unroll
                for (int mt = 0; mt < 4; ++mt)
                    a[mt] = *(const short8*)&w_t[(mt * 16 + lxx) * 296 + tap * 32 + kb * 8];
                #pragma unroll
                for (int rr = 0; rr < 4; ++rr) {
                    const int pbase = ((wv * 4 + rr + ky) * 18 + lxx + kx) * 40;
                    b1[rr] = *(const short8*)&in_t[pbase + kb * 8];
                    b2[rr] = *(const short8*)&in_t[pbase + (kb ^ 2) * 8];
                }
                #pragma unroll
                for (int mt = 0; mt < 4; ++mt)
                    #pragma unroll
                    for (int rr = 0; rr < 4; ++rr) {
                        acc[mt][rr] = __builtin_amdgcn_mfma_f32_16x16x32_bf16(
                            a[mt], b1[rr], acc[mt][rr], 0, 0, 0);
                        acc[mt][rr] = __builtin_amdgcn_mfma_f32_16x16x32_bf16(
                            a[mt], b2[rr], acc[mt][rr], 0, 0, 0);
                    }
            }
        }
    }

    const int x = x0 + lxx;
    const bool xok = (x < W);
    const long ob = to.o[b], rb = trr.o[b];
    #pragma unroll
    for (int mt = 0; mt < 4; ++mt) {
        const int col0 = cobase + mt * 16 + kb * 4;
        float bvv[4];
        #pragma unroll
        for (int j = 0; j < 4; ++j)
            bvv[j] = (col0 + j < O) ? bias[col0 + j] : 0.0f;
        #pragma unroll
        for (int rr = 0; rr < 4; ++rr) {
            const int y = y0 + wv * 4 + rr;
            if (y >= H) continue;
            #pragma unroll
            for (int j = 0; j < 4; ++j) {
                const int coj = col0 + j;
                if (coj >= O || !xok) continue;
                float v = acc[mt][rr][j] + bvv[j];
                if (hasres) v += res[rb + (long)coj * HW + (long)y * W + x];
                if (act == 1) v = fmaxf(v, 0.0f);
                else if (act == 2) v = (v >= 0.0f) ? v : 0.01f * v;
                out[ob + (long)coj * HW + (long)y * W + x] = v;
            }
        }
    }
}

// ---------------------------------------------------------------------------
// MaxPool2d(3,2,1) + LeakyReLU
// ---------------------------------------------------------------------------
__global__ __launch_bounds__(256) void pool_lrelu_k(
    const float* __restrict__ in, float* __restrict__ out, int H, int W)
{
    const int Ho = H / 2, Wo = W / 2;
    const int n = blockIdx.y;
    const int i = blockIdx.x * 256 + threadIdx.x;
    if (i >= Ho * Wo) return;
    const int ho = i / Wo, wo = i % Wo;
    const float* p = in + (long)n * H * W;
    float m = -1e30f;
    #pragma unroll
    for (int dy = 0; dy < 3; ++dy) {
        const int y = 2 * ho - 1 + dy;
        if (y < 0 || y >= H) continue;
        #pragma unroll
        for (int dx = 0; dx < 3; ++dx) {
            const int x = 2 * wo - 1 + dx;
            if (x < 0 || x >= W) continue;
            m = fmaxf(m, p[y * W + x]);
        }
    }
    out[(long)n * Ho * Wo + i] = (m >= 0.0f) ? m : 0.01f * m;
}

// Bilinear 2x upsample (half-pixel, edge clamp) then *2.0
__global__ __launch_bounds__(256) void resize2x_k(
    const float* __restrict__ in, float* __restrict__ out, int H, int W)
{
    const int Ho = 2 * H, Wo = 2 * W;
    const int n = blockIdx.y;
    const int i = blockIdx.x * 256 + threadIdx.x;
    if (i >= Ho * Wo) return;
    const int ho = i / Wo, wo = i % Wo;
    float cy = fminf(fmaxf(0.5f * (ho + 0.5f) - 0.5f, 0.0f), (float)(H - 1));
    float cx = fminf(fmaxf(0.5f * (wo + 0.5f) - 0.5f, 0.0f), (float)(W - 1));
    const int y0 = (int)cy, x0 = (int)cx;
    const int y1 = min(y0 + 1, H - 1), x1 = min(x0 + 1, W - 1);
    const float fy = cy - y0, fx = cx - x0;
    const float* p = in + (long)n * H * W;
    const float v = (1.0f - fy) * ((1.0f - fx) * p[y0 * W + x0] + fx * p[y0 * W + x1])
                  + fy * ((1.0f - fx) * p[y1 * W + x0] + fx * p[y1 * W + x1]);
    out[(long)n * Ho * Wo + i] = 2.0f * v;
}

__global__ __launch_bounds__(256) void copy_view_k(
    const float* __restrict__ src, float* __restrict__ dst, Tab8 td, int n)
{
    const int i = blockIdx.x * 256 + threadIdx.x;
    const int b = blockIdx.y;
    if (i < n) dst[td.o[b] + i] = src[(long)b * n + i];
}

// ---------------------------------------------------------------------------
// Modulated deformable conv v2: phase A (shared offset records), phase B
// (gather -> split-bf16 val), phase C (MFMA over K=576, exact half-swap).
// Block: 256 thr, 32 positions x 64 out-ch. 4 passes of 2 groups (9 kb).
// ---------------------------------------------------------------------------
__global__ __launch_bounds__(256, 2) void dcn_mfma_k(
    const float* __restrict__ xbase, Tab8 xoff,
    const float* __restrict__ om, long omstride,
    const unsigned short* __restrict__ wp,   // [36][64][32]
    const float* __restrict__ bias,
    float* __restrict__ out, long ostride,
    int H, int W)
{
    __shared__ unsigned short valb[9][32][40];   // 23,040 B
    __shared__ unsigned short wblk[9][64][40];   // 46,080 B (records overlay)
    float* rw4 = (float*)&wblk[0][0][0];         // [576][4]
    int* ridx = (int*)(rw4 + 576 * 4);           // [576]
    int* rdd  = ridx + 576;                      // [576]

    const int tid = threadIdx.x;
    const int vb = blockIdx.y;
    const int HW = H * W;
    const int pos0 = blockIdx.x * 32;
    const float* xv = xbase + xoff.o[vb];
    const float* omv = om + (long)vb * omstride;
    const int lane = tid & 63, wv = tid >> 6;
    const int lxx = lane & 15, kq = lane >> 4;
    const int sp = tid >> 3, sc = tid & 7;

    f32x4 acc[2];
    acc[0] = (f32x4){0.f, 0.f, 0.f, 0.f};
    acc[1] = (f32x4){0.f, 0.f, 0.f, 0.f};

    for (int gp = 0; gp < 4; ++gp) {
        __syncthreads();   // prior pass phase C done before records overwrite
        // ---- phase A: one record per (g2,k,pos) ----
        for (int r = tid; r < 576; r += 256) {
            const int p = r & 31;
            const int gk = r >> 5;            // 0..17
            const int g2 = (gk >= 9) ? 1 : 0;
            const int kk = gk - g2 * 9;
            const int g = gp * 2 + g2;
            const int pos = pos0 + p;
            const int hh = pos / W, ww = pos % W;
            const int ch = g * 9 + kk;
            const float dy = omv[(long)ch * HW + pos];
            const float dx = omv[(long)(72 + ch) * HW + pos];
            const float mv = omv[(long)(144 + ch) * HW + pos];
            const float m = 1.0f / (1.0f + expf(-mv));
            float py = dy + (float)(hh + kk / 3 - 1);
            float px = dx + (float)(ww + kk % 3 - 1);
            py = fminf(fmaxf(py, -8.0f), (float)H + 8.0f);
            px = fminf(fmaxf(px, -8.0f), (float)W + 8.0f);
            const float yf = floorf(py), xf = floorf(px);
            const float wy = py - yf, wx = px - xf;
            const int y0 = (int)yf, x0 = (int)xf;
            const int y1 = y0 + 1, x1 = x0 + 1;
            const bool yv0 = (y0 >= 0) && (y0 < H), yv1 = (y1 >= 0) && (y1 < H);
            const bool xv0_ = (x0 >= 0) && (x0 < W), xv1_ = (x1 >= 0) && (x1 < W);
            const int yc0 = min(max(y0, 0), H - 1), yc1 = min(max(y1, 0), H - 1);
            const int xc0 = min(max(x0, 0), W - 1), xc1 = min(max(x1, 0), W - 1);
            rw4[r * 4 + 0] = (yv0 && xv0_) ? (1.f - wy) * (1.f - wx) * m : 0.f;
            rw4[r * 4 + 1] = (yv0 && xv1_) ? (1.f - wy) * wx * m : 0.f;
            rw4[r * 4 + 2] = (yv1 && xv0_) ? wy * (1.f - wx) * m : 0.f;
            rw4[r * 4 + 3] = (yv1 && xv1_) ? wy * wx * m : 0.f;
            ridx[r] = yc0 * W + xc0;
            rdd[r] = (xc1 - xc0) | (((yc1 - yc0) * W) << 8);
        }
        __syncthreads();
        // ---- phase B: gather, write split-bf16 val ----
        #pragma unroll
        for (int g2 = 0; g2 < 2; ++g2) {
            const int g = gp * 2 + g2;
            const float* xc = xv + (long)(g * 8 + sc) * HW;
            const int kbase = g * 72 + sc * 9;
            #pragma unroll
            for (int kk = 0; kk < 9; ++kk) {
                const int r = (g2 * 9 + kk) * 32 + sp;
                const float4 w4 = *(const float4*)&rw4[r * 4];
                const int i00 = ridx[r];
                const int dd = rdd[r];
                const int dx01 = dd & 0xff, dyW = dd >> 8;
                const float v = w4.x * xc[i00] + w4.y * xc[i00 + dx01]
                              + w4.z * xc[i00 + dyW] + w4.w * xc[i00 + dyW + dx01];
                const int k = kbase + kk;
                const int q = k & 15;
                const int kb = (k >> 4) - gp * 9;
                const unsigned short hi = f2bf(v);
                valb[kb][sp][q] = hi;
                valb[kb][sp][q + 16] = f2bf(v - bf2f(hi));
            }
        }
        __syncthreads();
        // ---- stage weights (overwrites record area) ----
        {
            const unsigned short* src = wp + (long)gp * 9 * 64 * 32;
            #pragma unroll
            for (int i = 0; i < 9; ++i) {
                const int c = tid + (i << 8);      // 2304 short8 chunks
                const int kb = c >> 8, within = c & 255;
                const int o = within >> 2, part = within & 3;
                *(short8*)&wblk[kb][o][part * 8] =
                    *(const short8*)(src + ((kb * 64 + o) * 32 + part * 8));
            }
        }
        __syncthreads();
        // ---- phase C: MFMA ----
        #pragma unroll
        for (int kb = 0; kb < 9; ++kb) {
            const short8 a = *(const short8*)&wblk[kb][wv * 16 + lxx][kq * 8];
            #pragma unroll
            for (int pt = 0; pt < 2; ++pt) {
                const short8 b1 = *(const short8*)&valb[kb][pt * 16 + lxx][kq * 8];
                const short8 b2 = *(const short8*)&valb[kb][pt * 16 + lxx][(kq ^ 2) * 8];
                acc[pt] = __builtin_amdgcn_mfma_f32_16x16x32_bf16(a, b1, acc[pt], 0, 0, 0);
                acc[pt] = __builtin_amdgcn_mfma_f32_16x16x32_bf16(a, b2, acc[pt], 0, 0, 0);
            }
        }
    }
    float* ov = out + (long)vb * ostride;
    #pragma unroll
    for (int pt = 0; pt < 2; ++pt)
        #pragma unroll
        for (int j = 0; j < 4; ++j) {
            const int o = wv * 16 + kq * 4 + j;
            const int p = pt * 16 + lxx;
            ov[(long)o * HW + pos0 + p] = acc[pt][j] + bias[o];
        }
}

// ---------------------------------------------------------------------------
// Host orchestration
// ---------------------------------------------------------------------------
namespace {

struct MOff {
    const unsigned short *c1w; const float* c1b;
    const unsigned short *rw1; const float* rb1;
    const unsigned short *rw2; const float* rb2;
    const unsigned short *c2w; const float* c2b;
};

inline Tab8 tab(long stride) {
    Tab8 t;
    for (int i = 0; i < 8; ++i) t.o[i] = (long)i * stride;
    return t;
}

inline void conv_b(hipStream_t s,
                   const float* i1, Tab8 t1, int c1,
                   const float* i2, Tab8 t2, int c2,
                   const unsigned short* w, const float* bias,
                   const float* res, Tab8 trr, int hasres,
                   float* out, Tab8 to,
                   int O, int Opad, int H, int W, int B, int act)
{
    dim3 grid(((H + 15) / 16) * ((W + 15) / 16), Opad / 64, B);
    conv_mfma_k<<<grid, 256, 0, s>>>(i1, t1, c1, i2, t2, c2, w, bias,
                                     res, trr, hasres, out, to, O, H, W, act);
}

inline void offnetB(hipStream_t s, const MOff& p,
                    const float* cfb, Tab8 tcf, const float* lfb, Tab8 tlf,
                    float* t1, float* u, float* outp, int H, int W, int B)
{
    const long hw = (long)H * W;
    const Tab8 tz = tab(64 * hw);
    conv_b(s, cfb, tcf, 64, lfb, tlf, 64, p.c1w, p.c1b,
           nullptr, tz, 0, t1, tz, 64, 64, H, W, B, 2);
    for (int r = 0; r < 2; ++r) {
        conv_b(s, t1, tz, 64, nullptr, tz, 0, p.rw1, p.rb1,
               nullptr, tz, 0, u, tz, 64, 64, H, W, B, 1);
        conv_b(s, u, tz, 64, nullptr, tz, 0, p.rw2, p.rb2,
               t1, tz, 1, t1, tz, 64, 64, H, W, B, 0);
    }
    conv_b(s, t1, tz, 64, nullptr, tz, 0, p.c2w, p.c2b,
           nullptr, tz, 0, outp, tz, 64, 64, H, W, B, 2);
}

// om conv + dcn + write-back, chunked so om fits in its (8*SZ float) region.
inline void dcnB(hipStream_t s, const float* lapbase, Tab8 tlf,
                 const float* feat,
                 const unsigned short* Wom, const float* omb,
                 const unsigned short* Wdcn, const float* dcnb,
                 float* om, float* tmp, int H, int W, int VB)
{
    const long hw = (long)H * W;
    const long cap = 8L * 64 * 25600;          // floats available for om
    int cmax = (int)(cap / (216 * hw));
    if (cmax > VB) cmax = VB;
    if (cmax < 1) cmax = 1;
    for (int c0 = 0; c0 < VB; c0 += cmax) {
        const int nc = (VB - c0 < cmax) ? (VB - c0) : cmax;
        Tab8 tfeat = tab(0), tx = tab(0), tdst = tab(0);
        for (int i = 0; i < nc; ++i) {
            tfeat.o[i] = (long)(c0 + i) * 64 * hw;
            tx.o[i]    = tlf.o[c0 + i];
            tdst.o[i]  = tlf.o[c0 + i];
        }
        conv_b(s, feat, tfeat, 64, nullptr, tfeat, 0, Wom, omb,
               nullptr, tfeat, 0, om, tab(216 * hw), 216, 256, H, W, nc, 0);
        dim3 gd((int)(hw / 32), nc);
        dcn_mfma_k<<<gd, 256, 0, s>>>(lapbase, tx, om, 216 * hw, Wdcn, dcnb,
                                      tmp, 64 * hw, H, W);
        dim3 gc((int)((64 * hw + 255) / 256), nc);
        copy_view_k<<<gc, 256, 0, s>>>(tmp, (float*)lapbase, tdst, (int)(64 * hw));
    }
}

} // namespace

extern "C" void kernel_launch(void* const* d_in, const int* in_sizes, int n_in,
                              void* d_out, int out_size, void* d_ws, size_t ws_size,
                              hipStream_t stream)
{
    (void)in_sizes; (void)n_in; (void)out_size; (void)ws_size;
    const float* P[39];
    for (int k = 0; k < 39; ++k) P[k] = (const float*)d_in[k];
    const float* images = P[0];

    const int HW0 = 160 * 160, HW1 = 80 * 80, HW2 = 40 * 40;
    float* L0 = (float*)d_out;
    float* L1 = L0 + (long)6 * 64 * HW0;
    float* L2 = L1 + (long)6 * 64 * HW1;

    // ---- workspace layout: 16*SZ floats (~105 MB) + weights (~3.5 MB) ----
    const long SZ = (long)64 * HW0;          // 1,638,400 floats
    float* ws = (float*)d_ws;
    float* OFF_A = ws;                        // [0, 4SZ)   po chain
    float* OFF_B = ws + 4 * SZ;               // [4, 8SZ)   offnet-stage / TDCN
    float* POUP  = ws + 8 * SZ;               // [8, 12SZ)  po_up*2; U scratch
    float* T1    = ws + 12 * SZ;              // [12, 16SZ) offnet hidden
    float* U     = POUP;                      // alias (safe: see ordering)
    float* OM    = ws + 8 * SZ;               // overlays POUP+T1 (8SZ cap)
    float* A     = ws;                        // features phase (6SZ)
    float* Bb    = ws + 6 * SZ;               // features phase (6SZ)
    unsigned short* WP = (unsigned short*)(ws + 16 * SZ);

    // ---- weight prep ----
    const int widx[18] = {1,3,5,7,9,11,13,15,17,19,21,23,25,27,29,31,33,35};
    const int wci[18]  = {3,64,64,64,64,64,64,64,64,128,64,64,64,128,64,64,64,64};
    const int wo_[18]  = {64,64,64,64,64,64,64,64,64,64,64,64,64,64,64,64,64,216};
    WDescs ds;
    long off = 0;
    long woff[18];
    for (int i = 0; i < 18; ++i) {
        const int opad = (wo_[i] + 63) / 64 * 64;
        const int ncib = (wci[i] + 15) / 16;
        ds.d[i].w = P[widx[i]]; ds.d[i].Ci = wci[i]; ds.d[i].O = wo_[i];
        ds.d[i].Opad = opad; ds.d[i].off = off;
        woff[i] = off;
        off += (long)ncib * opad * 288;
    }
    unsigned short* WPD = WP + off;           // dcn weights [36][64][32]
    prep_w_k<<<dim3(1152, 18), 256, 0, stream>>>(ds, WP);
    prep_dcnw_k<<<dim3(288), 256, 0, stream>>>(P[37], WPD);

    const unsigned short* Wc0a  = WP + woff[0];
    const unsigned short* Wc0r1 = WP + woff[1];
    const unsigned short* Wc0r2 = WP + woff[2];
    const unsigned short* Wc0b  = WP + woff[3];
    const unsigned short* Wd11  = WP + woff[4];
    const unsigned short* Wd12  = WP + woff[5];
    const unsigned short* Wd21  = WP + woff[6];
    const unsigned short* Wd22  = WP + woff[7];
    const unsigned short* Wdc   = WP + woff[8];
    MOff offp = {WP + woff[9],  P[20], WP + woff[10], P[22],
                 WP + woff[11], P[24], WP + woff[12], P[26]};
    MOff mrgp = {WP + woff[13], P[28], WP + woff[14], P[30],
                 WP + woff[15], P[32], WP + woff[16], P[34]};
    const unsigned short* Wom = WP + woff[17];
    const float* dcn_om_b = P[36];
    const float* dcn_b = P[38];

    // ---------------- feature extraction (B = 6, contiguous) --------------
    const Tab8 ti = tab((long)3 * HW0);
    const Tab8 t60 = tab((long)64 * HW0);
    const Tab8 t61 = tab((long)64 * HW1);
    conv_b(stream, images, ti, 3, nullptr, t60, 0, Wc0a, P[2],
           nullptr, t60, 0, A, t60, 64, 64, 160, 160, 6, 0);
    conv_b(stream, A, t60, 64, nullptr, t60, 0, Wc0r1, P[4],
           nullptr, t60, 0, Bb, t60, 64, 64, 160, 160, 6, 1);
    conv_b(stream, Bb, t60, 64, nullptr, t60, 0, Wc0r2, P[6],
           A, t60, 1, A, t60, 64, 64, 160, 160, 6, 0);
    conv_b(stream, A, t60, 64, nullptr, t60, 0, Wc0b, P[8],
           nullptr, t60, 0, L0, t60, 64, 64, 160, 160, 6, 2);

    conv_b(stream, L0, t60, 64, nullptr, t60, 0, Wd11, P[10],
           nullptr, t60, 0, Bb, t60, 64, 64, 160, 160, 6, 1);
    conv_b(stream, Bb, t60, 64, nullptr, t60, 0, Wd12, P[12],
           L0, t60, 1, A, t60, 64, 64, 160, 160, 6, 0);
    conv_b(stream, A, t60, 64, nullptr, t60, 0, Wd21, P[14],
           nullptr, t60, 0, Bb, t60, 64, 64, 160, 160, 6, 1);
    conv_b(stream, Bb, t60, 64, nullptr, t60, 0, Wd22, P[16],
           A, t60, 1, A, t60, 64, 64, 160, 160, 6, 0);
    conv_b(stream, A, t60, 64, nullptr, t60, 0, Wdc, P[18],
           nullptr, t60, 0, Bb, t60, 64, 64, 160, 160, 6, 0);
    {
        dim3 gp((HW1 + 255) / 256, 6 * 64);
        pool_lrelu_k<<<gp, 256, 0, stream>>>(Bb, L1, 160, 160);
    }
    conv_b(stream, L1, t61, 64, nullptr, t61, 0, Wd11, P[10],
           nullptr, t61, 0, Bb, t61, 64, 64, 80, 80, 6, 1);
    conv_b(stream, Bb, t61, 64, nullptr, t61, 0, Wd12, P[12],
           L1, t61, 1, A, t61, 64, 64, 80, 80, 6, 0);
    conv_b(stream, A, t61, 64, nullptr, t61, 0, Wd21, P[14],
           nullptr, t61, 0, Bb, t61, 64, 64, 80, 80, 6, 1);
    conv_b(stream, Bb, t61, 64, nullptr, t61, 0, Wd22, P[16],
           A, t61, 1, A, t61, 64, 64, 80, 80, 6, 0);
    conv_b(stream, A, t61, 64, nullptr, t61, 0, Wdc, P[18],
           nullptr, t61, 0, Bb, t61, 64, 64, 80, 80, 6, 0);
    {
        dim3 gp((HW2 + 255) / 256, 6 * 64);
        pool_lrelu_k<<<gp, 256, 0, stream>>>(Bb, L2, 80, 80);
    }

    // ---------------- view loop: batched {0,1}, then {2} -------------------
    // Buffer plan per level (po handoff always through OFF_A):
    //   L2: offp -> OFF_A;                       dcn(feat=OFF_A, tmp=OFF_B)
    //   L1: offp -> OFF_B; resize OFF_A -> POUP; mrg(OFF_B,POUP) -> OFF_A;
    //       dcn(feat=OFF_A, tmp=OFF_B)
    //   L0: same as L1.
    const int cv = 1;
    for (int pass = 0; pass < 2; ++pass) {
        const int vs01[2] = {0, 1};
        const int vs2[1] = {2};
        const int* vlist = pass ? vs2 : vs01;
        const int nv = pass ? 1 : 2;
        const int VB = nv * 2;

        Tab8 tcf2 = tab(0), tlf2 = tab(0), tcf1 = tab(0), tlf1 = tab(0),
             tcf0 = tab(0), tlf0 = tab(0);
        for (int i = 0; i < VB; ++i) {
            const int v = vlist[i >> 1], b = i & 1;
            tlf2.o[i] = ((long)b * 3 + v)  * 64 * HW2;
            tcf2.o[i] = ((long)b * 3 + cv) * 64 * HW2;
            tlf1.o[i] = ((long)b * 3 + v)  * 64 * HW1;
            tcf1.o[i] = ((long)b * 3 + cv) * 64 * HW1;
            tlf0.o[i] = ((long)b * 3 + v)  * 64 * HW0;
            tcf0.o[i] = ((long)b * 3 + cv) * 64 * HW0;
        }
        // ---- level 2 (40x40) ----
        offnetB(stream, offp, L2, tcf2, L2, tlf2, T1, U, OFF_A, 40, 40, VB);
        dcnB(stream, L2, tlf2, OFF_A, Wom, dcn_om_b, WPD, dcn_b,
             OM, OFF_B, 40, 40, VB);
        // ---- level 1 (80x80) ----
        offnetB(stream, offp, L1, tcf1, L1, tlf1, T1, U, OFF_B, 80, 80, VB);
        {
            dim3 gr((HW1 + 255) / 256, VB * 64);
            resize2x_k<<<gr, 256, 0, stream>>>(OFF_A, POUP, 40, 40);
        }
        offnetB(stream, mrgp, OFF_B, tab((long)64 * HW1), POUP, tab((long)64 * HW1),
                T1, U, OFF_A, 80, 80, VB);
        dcnB(stream, L1, tlf1, OFF_A, Wom, dcn_om_b, WPD, dcn_b,
             OM, OFF_B, 80, 80, VB);
        // ---- level 0 (160x160) ----
        offnetB(stream, offp, L0, tcf0, L0, tlf0, T1, U, OFF_B, 160, 160, VB);
        {
            dim3 gr((HW0 + 255) / 256, VB * 64);
            resize2x_k<<<gr, 256, 0, stream>>>(OFF_A, POUP, 80, 80);
        }
        offnetB(stream, mrgp, OFF_B, tab((long)64 * HW0), POUP, tab((long)64 * HW0),
                T1, U, OFF_A, 160, 160, VB);
        dcnB(stream, L0, tlf0, OFF_A, Wom, dcn_om_b, WPD, dcn_b,
             OM, OFF_B, 160, 160, VB);
    }
}